// Round 13
// baseline (1103.838 us; speedup 1.0000x reference)
//
#include <hip/hip_runtime.h>

// Problem constants (match reference)
#define USER_COUNT 100000
#define ITEM_COUNT 50000
#define N_NODES    (USER_COUNT + ITEM_COUNT)   // 150000
#define EMB        128
#define NNZ        1600000
#define BATCH      4096

// Static bucket regions. R13: BSHIFT=8 (256 rows/bucket = blockDim of the
// fine phase), 586 buckets. Binomial mean 2731, sigma 52; CAP=3072 is a
// 6.5-sigma margin (P(overflow) ~ 1e-8 over 586 buckets).
#define BSHIFT  8
#define BROWS   (1 << BSHIFT)                                  // 256
#define NBUCKET ((N_NODES + BROWS - 1) >> BSHIFT)              // 586
#define CAP     3072
#define TILE    2048                                           // binning LDS 16 KB
#define NB_BIN  ((NNZ + TILE - 1) / TILE)                      // 782 binning tasks
#define NB_CONV 9375                                           // conversion tasks (exact)
#define MARK_BLKS 32
#define NBLK    ((N_NODES + 7) / 8)                            // 18750 spmm tasks
#define FIN_TASKS (2 * BATCH / 8)                              // 1024 final tasks
#define GRID    1024                                           // 32 leaves x 32 blocks

// fp8 per-layer scaling (power-of-2; folded rescale = 0.25 both layers).
#define SCALE0  16384.0f
#define RESCALE 0.25f
#define INV0    (1.0f / 16384.0f)
#define INV1    (1.0f / 4096.0f)
#define INV2    (1.0f / 1024.0f)
#define ROW_U32 (EMB / 4)      // 32 u32 = 128 B fp8 row = exactly one line

typedef unsigned int uint32;
typedef unsigned long long uint64;
typedef float f32x2 __attribute__((ext_vector_type(2)));

// Session ledger:
//  R1-R5 (closed): full-line gathers only; 4-edge unroll = required load
//     depth; NT hints, feature-split, col-partition all regressed.
//  R6 (validated): DAG collapse pays ~10+ us/boundary.
//  R7 (closed): fp8 only through edge-sums, never direct reads.
//  R8 (validated): full-fp8 buffers. spmm 43 us, FETCH 90 MB.
//  R9-R11 (closed): spmm at fill/latency floor; prep invariant to occupancy
//     (R10) and bucket parallelism (R11).
//  R12 (validated, 235.1): bin_fine LDS-staged coalesced csr4 write (+5.6).
//     AUDIT: kernels sum ~142 us; ~93 us = 5 launch boundaries (~15-19 each).
//  R13 (this): persistent mega-kernel, 1024 blocks co-resident (LDS 25.8 KB
//     -> 6 blocks/CU capacity 1536), 4 two-level software grid barriers
//     (threadfence = L2 wb/inv handles XCD non-coherence; that flush happens
//     at kernel boundaries today anyway). Predicted total ~180-210.
//     Falsification: >=230 -> revert R12, declare roofline.

// Edge record: [val_f32_top14 : 14][col : 18]. 2-op decode; error enters
// only through edge-sums (averages down).
__device__ __forceinline__ float decv(uint32 rec)
{
    return __uint_as_float((rec >> 18) << 17);
}
__device__ __forceinline__ uint32 enc14(float v)
{
    uint32 u = __float_as_uint(v);
    return ((u + 0xFFFFu + ((u >> 17) & 1u)) >> 17) & 0x3FFFu;
}

// fp8 e4m3 HW conversion helpers (gfx950 OCP; validated R8-R12).
__device__ __forceinline__ void fma4_fp8(uint32 g, float v, float4& acc)
{
    f32x2 lo = __builtin_amdgcn_cvt_pk_f32_fp8(g, false);
    f32x2 hi = __builtin_amdgcn_cvt_pk_f32_fp8(g, true);
    acc.x += v * lo.x;
    acc.y += v * lo.y;
    acc.z += v * hi.x;
    acc.w += v * hi.y;
}
__device__ __forceinline__ uint32 enc_fp8x4(float4 a, float s)
{
    uint32 r = 0;
    r = __builtin_amdgcn_cvt_pk_fp8_f32(a.x * s, a.y * s, r, false);
    r = __builtin_amdgcn_cvt_pk_fp8_f32(a.z * s, a.w * s, r, true);
    return r;
}

// Shared-memory union: binning phase (25.8 KB) vs fine phase (13.3 KB).
// Max member 25,776 B -> 6 blocks/CU by LDS; grid 1024 <= capacity 1536.
struct BinSh {
    uint64 stage[TILE];        // 16384 B
    int cnt[NBUCKET];          //  2344 B
    int offs[NBUCKET];
    int base[NBUCKET];
    int cur[NBUCKET];
    int wsum[4];
};
struct FineSh {
    uint32 stageS[CAP];        // 12288 B
    int hist[BROWS];           //  1024 B
    int wsum[4];
};
union SharedU { BinSh bin; FineSh fine; };

// ---------------------------------------------------------------------------
// Two-level grid barrier (32 leaves x 32 blocks). Release: threadfence
// (L2 writeback) then counter tree; acquire: spin on generation word then
// threadfence (invalidate). RMW chains on the counters form a release
// sequence, so all pre-barrier writes are visible after the gen bump.
// bar[0]=gen, bar[32]=root, bar[64+leaf*32]=leaf counters.
// ---------------------------------------------------------------------------
__device__ __forceinline__ void grid_sync(int* bar)
{
    __syncthreads();
    if (threadIdx.x == 0) {
        __threadfence();
        int gen = __hip_atomic_load(&bar[0], __ATOMIC_RELAXED, __HIP_MEMORY_SCOPE_AGENT);
        int* lc = &bar[64 + (blockIdx.x >> 5) * 32];
        int p = __hip_atomic_fetch_add(lc, 1, __ATOMIC_ACQ_REL, __HIP_MEMORY_SCOPE_AGENT);
        if (p == 31) {
            __hip_atomic_store(lc, 0, __ATOMIC_RELAXED, __HIP_MEMORY_SCOPE_AGENT);
            int q = __hip_atomic_fetch_add(&bar[32], 1, __ATOMIC_ACQ_REL, __HIP_MEMORY_SCOPE_AGENT);
            if (q == 31) {
                __hip_atomic_store(&bar[32], 0, __ATOMIC_RELAXED, __HIP_MEMORY_SCOPE_AGENT);
                __hip_atomic_fetch_add(&bar[0], 1, __ATOMIC_RELEASE, __HIP_MEMORY_SCOPE_AGENT);
            }
        }
        while (__hip_atomic_load(&bar[0], __ATOMIC_ACQUIRE, __HIP_MEMORY_SCOPE_AGENT) == gen)
            __builtin_amdgcn_s_sleep(8);
        __threadfence();
    }
    __syncthreads();
}

// ---------------------------------------------------------------------------
// SpMM row task (R12-proven body). 8 rows/task, half-wave per row, ONE dword
// per edge per lane (full 128 B line per half-wave), 4-edge unroll.
// ---------------------------------------------------------------------------
__device__ __forceinline__ void spmm_task(const uint32* __restrict__ row_info4,
                                          const uint32* __restrict__ csr4,
                                          const uint32* __restrict__ x,
                                          uint32* __restrict__ y,
                                          const unsigned char* __restrict__ mark,
                                          int blk, int t)
{
    int half = t >> 5;
    int r = blk * 8 + half;
    if (r >= N_NODES) return;
    if (mark && !mark[r]) return;
    uint32 j = t & 31;
    uint32 info = row_info4[r];
    int s = (int)(info & 0xFFFFFFu);
    int e = s + (int)(info >> 24);
    float4 acc = { 0.f, 0.f, 0.f, 0.f };
    for (int k = s; k < e; k += 4) {
        int i1 = (k + 1 < e) ? k + 1 : e - 1;
        int i2 = (k + 2 < e) ? k + 2 : e - 1;
        int i3 = (k + 3 < e) ? k + 3 : e - 1;
        uint32 r0 = csr4[k];
        uint32 r1 = csr4[i1];
        uint32 r2 = csr4[i2];
        uint32 r3 = csr4[i3];
        float v0 = decv(r0);
        float v1 = (k + 1 < e) ? decv(r1) : 0.f;
        float v2 = (k + 2 < e) ? decv(r2) : 0.f;
        float v3 = (k + 3 < e) ? decv(r3) : 0.f;
        uint32 g0 = x[(r0 & 0x3FFFFu) * ROW_U32 + j];
        uint32 g1 = x[(r1 & 0x3FFFFu) * ROW_U32 + j];
        uint32 g2 = x[(r2 & 0x3FFFFu) * ROW_U32 + j];
        uint32 g3 = x[(r3 & 0x3FFFFu) * ROW_U32 + j];
        fma4_fp8(g0, v0, acc);
        fma4_fp8(g1, v1, acc);
        fma4_fp8(g2, v2, acc);
        fma4_fp8(g3, v3, acc);
    }
    y[(uint32)r * ROW_U32 + j] = enc_fp8x4(acc, RESCALE);
}

// Final task (R8 rule: fp8 only through edge-sums). 8 output rows/task.
__device__ __forceinline__ void final_task(const uint32* __restrict__ row_info4,
                                           const uint32* __restrict__ csr4,
                                           const uint32* __restrict__ ego8,
                                           const uint32* __restrict__ buf0,
                                           const uint32* __restrict__ buf1,
                                           const float* __restrict__ user_emb,
                                           const float* __restrict__ item_emb,
                                           const int* __restrict__ users,
                                           const int* __restrict__ items,
                                           float* __restrict__ out,
                                           int blk, int t)
{
    int half = t >> 5;
    int b = blk * 8 + half;
    if (b >= 2 * BATCH) return;
    int node;
    const float* ego0;
    if (b < BATCH) {
        node = users[b];
        ego0 = user_emb + (size_t)node * EMB;
    } else {
        int it = items[b - BATCH];
        node = USER_COUNT + it;
        ego0 = item_emb + (size_t)it * EMB;
    }
    uint32 j = t & 31;
    int j4 = (int)j * 4;
    uint32 info = row_info4[node];
    int s = (int)(info & 0xFFFFFFu);
    int e = s + (int)(info >> 24);
    float4 a1 = { 0.f, 0.f, 0.f, 0.f };
    float4 a2 = { 0.f, 0.f, 0.f, 0.f };
    float4 a3 = { 0.f, 0.f, 0.f, 0.f };
    for (int k = s; k < e; k += 4) {
        int i1 = (k + 1 < e) ? k + 1 : e - 1;
        int i2 = (k + 2 < e) ? k + 2 : e - 1;
        int i3 = (k + 3 < e) ? k + 3 : e - 1;
        uint32 r0 = csr4[k];
        uint32 r1 = csr4[i1];
        uint32 r2 = csr4[i2];
        uint32 r3 = csr4[i3];
        float v0 = decv(r0);
        float v1 = (k + 1 < e) ? decv(r1) : 0.f;
        float v2 = (k + 2 < e) ? decv(r2) : 0.f;
        float v3 = (k + 3 < e) ? decv(r3) : 0.f;
        uint32 o0 = (r0 & 0x3FFFFu) * ROW_U32 + j;
        uint32 o1 = (r1 & 0x3FFFFu) * ROW_U32 + j;
        uint32 o2 = (r2 & 0x3FFFFu) * ROW_U32 + j;
        uint32 o3 = (r3 & 0x3FFFFu) * ROW_U32 + j;
        uint32 e0 = ego8[o0], e1 = ego8[o1], e2 = ego8[o2], e3 = ego8[o3];
        uint32 b00 = buf0[o0], b01 = buf0[o1], b02 = buf0[o2], b03 = buf0[o3];
        uint32 b10 = buf1[o0], b11 = buf1[o1], b12 = buf1[o2], b13 = buf1[o3];
        fma4_fp8(e0, v0, a1);
        fma4_fp8(e1, v1, a1);
        fma4_fp8(e2, v2, a1);
        fma4_fp8(e3, v3, a1);
        fma4_fp8(b00, v0, a2);
        fma4_fp8(b01, v1, a2);
        fma4_fp8(b02, v2, a2);
        fma4_fp8(b03, v3, a2);
        fma4_fp8(b10, v0, a3);
        fma4_fp8(b11, v1, a3);
        fma4_fp8(b12, v2, a3);
        fma4_fp8(b13, v3, a3);
    }
    float4 a0 = *(const float4*)(ego0 + j4);
    float4 o;
    o.x = 0.25f * (a0.x + a1.x * INV0 + a2.x * INV1 + a3.x * INV2);
    o.y = 0.25f * (a0.y + a1.y * INV0 + a2.y * INV1 + a3.y * INV2);
    o.z = 0.25f * (a0.z + a1.z * INV0 + a2.z * INV1 + a3.z * INV2);
    o.w = 0.25f * (a0.w + a1.w * INV0 + a2.w * INV1 + a3.w * INV2);
    *(float4*)(out + (size_t)b * EMB + j4) = o;
}

// ---------------------------------------------------------------------------
// Persistent mega-kernel: 5 phases, 4 grid barriers, zero launch boundaries.
// Grid 1024 blocks x 256 thr, co-resident by construction (LDS 25.8 KB ->
// 6 blocks/CU capacity; launch_bounds(256,5) caps VGPR; grid < capacity).
// ---------------------------------------------------------------------------
__global__ __launch_bounds__(256, 5)
void mega(const float* __restrict__ user_emb,
          const float* __restrict__ item_emb,
          const float* __restrict__ vals,
          const int* __restrict__ rows,
          const int* __restrict__ cols,
          const int* __restrict__ users,
          const int* __restrict__ items,
          int* __restrict__ cursor,
          int* __restrict__ bar,
          uint64* __restrict__ binned,
          uint32* __restrict__ ego,
          uint32* __restrict__ buf0,
          uint32* __restrict__ buf1,
          unsigned char* __restrict__ mark,
          uint32* __restrict__ row_info4,
          uint32* __restrict__ csr4,
          float* __restrict__ out)
{
    __shared__ SharedU sh;
    int t = threadIdx.x;
    int bid = blockIdx.x;

    // ---- Phase A: coarse binning (782 tasks) + fp8 conversion (9375) ----
    for (int w = bid; w < NB_BIN + NB_CONV; w += GRID) {
        if (w >= NB_BIN) {
            int c = w - NB_BIN;
            size_t tt = (size_t)c * 256 + t;
            if (tt < (N_NODES + 3) / 4) ((uint32*)mark)[tt] = 0;
            size_t b0 = tt * 8;
            if (b0 < (size_t)N_NODES * EMB) {
                const size_t ue = (size_t)USER_COUNT * EMB;
                const float* src = (b0 < ue) ? user_emb + b0
                                             : item_emb + (b0 - ue);
                float4 a = *(const float4*)(src);
                float4 bb = *(const float4*)(src + 4);
                uint2 o;
                o.x = enc_fp8x4(a, SCALE0);
                o.y = enc_fp8x4(bb, SCALE0);
                *(uint2*)(ego + tt * 2) = o;
            }
        } else {
            int tileBase = w * TILE;
            int tileCount = min(TILE, NNZ - tileBase);
            for (int i = t; i < NBUCKET; i += 256) { sh.bin.cnt[i] = 0; sh.bin.cur[i] = 0; }
            __syncthreads();
            for (int i = t; i < tileCount; i += 256)
                atomicAdd(&sh.bin.cnt[rows[tileBase + i] >> BSHIFT], 1);
            __syncthreads();
            // exclusive scan cnt -> offs (3 chunks of 256)
            {
                int lane = t & 63, wid = t >> 6;
                int running = 0;
                for (int c0 = 0; c0 < NBUCKET; c0 += 256) {
                    int idx = c0 + t;
                    int mine = (idx < NBUCKET) ? sh.bin.cnt[idx] : 0;
                    int v = mine;
                    #pragma unroll
                    for (int off = 1; off <= 32; off <<= 1) {
                        int u = __shfl_up(v, off, 64);
                        if (lane >= off) v += u;
                    }
                    if (lane == 63) sh.bin.wsum[wid] = v;
                    __syncthreads();
                    int add = 0;
                    for (int w2 = 0; w2 < wid; ++w2) add += sh.bin.wsum[w2];
                    if (idx < NBUCKET) sh.bin.offs[idx] = running + v + add - mine;
                    running += sh.bin.wsum[0] + sh.bin.wsum[1] + sh.bin.wsum[2] + sh.bin.wsum[3];
                    __syncthreads();
                }
            }
            for (int i = t; i < NBUCKET; i += 256)
                sh.bin.base[i] = atomicAdd(&cursor[i], sh.bin.cnt[i]);
            __syncthreads();
            for (int i = t; i < tileCount; i += 256) {
                int r = rows[tileBase + i];
                int c = cols[tileBase + i];
                float v = vals[tileBase + i];
                int b = r >> BSHIFT;
                int p = sh.bin.offs[b] + atomicAdd(&sh.bin.cur[b], 1);
                sh.bin.stage[p] = ((uint64)enc14(v) << 36) | ((uint64)(uint32)r << 18) | (uint32)c;
            }
            __syncthreads();
            for (int i = t; i < tileCount; i += 256) {
                uint64 rec = sh.bin.stage[i];
                int r = (int)((rec >> 18) & 0x3FFFFu);
                int b = r >> BSHIFT;
                int dest = b * CAP + sh.bin.base[b] + (i - sh.bin.offs[b]);
                binned[dest] = rec;
            }
            __syncthreads();
        }
    }

    grid_sync(bar);

    // ---- Phase B: fine bin (586 buckets; hist[256] == blockDim) ----
    for (int b = bid; b < NBUCKET; b += GRID) {
        int lo = b * CAP;
        int hi = lo + cursor[b];
        int n = hi - lo;
        sh.fine.hist[t] = 0;
        __syncthreads();
        for (int i = lo + t; i < hi; i += 256) {
            int r = (int)((binned[i] >> 18) & 0x3FFFFu);
            atomicAdd(&sh.fine.hist[r & (BROWS - 1)], 1);
        }
        __syncthreads();
        int myVal = sh.fine.hist[t];
        int lane = t & 63, wid = t >> 6;
        int v = myVal;
        #pragma unroll
        for (int off = 1; off <= 32; off <<= 1) {
            int u = __shfl_up(v, off, 64);
            if (lane >= off) v += u;
        }
        if (lane == 63) sh.fine.wsum[wid] = v;
        __syncthreads();
        int add = 0;
        for (int w2 = 0; w2 < wid; ++w2) add += sh.fine.wsum[w2];
        int excl = add + v - myVal;
        int grow = (b << BSHIFT) + t;
        if (grow < N_NODES)
            row_info4[grow] = (uint32)(lo + excl) | ((uint32)myVal << 24);
        sh.fine.hist[t] = excl;
        __syncthreads();
        for (int i = lo + t; i < hi; i += 256) {
            uint64 rec = binned[i];
            uint32 c = (uint32)(rec & 0x3FFFFu);
            int r = (int)((rec >> 18) & 0x3FFFFu);
            uint32 v14 = (uint32)(rec >> 36) & 0x3FFFu;
            int pos = atomicAdd(&sh.fine.hist[r & (BROWS - 1)], 1);
            sh.fine.stageS[pos] = (v14 << 18) | c;
        }
        __syncthreads();
        for (int i = t; i < n; i += 256)
            csr4[lo + i] = sh.fine.stageS[i];
        __syncthreads();
    }

    grid_sync(bar);

    // ---- Phase C: layer 1 (ego -> buf0) + mark_needed (32 lead tasks) ----
    for (int w = bid; w < MARK_BLKS + NBLK; w += GRID) {
        if (w < MARK_BLKS) {
            int b = w * 256 + t;
            if (b < 2 * BATCH) {
                int node = (b < BATCH) ? users[b] : USER_COUNT + items[b - BATCH];
                mark[node] = 1;
                uint32 info = row_info4[node];
                int s = (int)(info & 0xFFFFFFu);
                int e = s + (int)(info >> 24);
                for (int k = s; k < e; ++k)
                    mark[csr4[k] & 0x3FFFFu] = 1;
            }
        } else {
            spmm_task(row_info4, csr4, ego, buf0, (const unsigned char*)0, w - MARK_BLKS, t);
        }
    }

    grid_sync(bar);

    // ---- Phase D: layer 2 (buf0 -> buf1, masked) ----
    for (int w = bid; w < NBLK; w += GRID)
        spmm_task(row_info4, csr4, buf0, buf1, mark, w, t);

    grid_sync(bar);

    // ---- Phase E: final fused gather (1024 tasks) ----
    for (int w = bid; w < FIN_TASKS; w += GRID)
        final_task(row_info4, csr4, ego, buf0, buf1,
                   user_emb, item_emb, users, items, out, w, t);
}

extern "C" void kernel_launch(void* const* d_in, const int* in_sizes, int n_in,
                              void* d_out, int out_size, void* d_ws, size_t ws_size,
                              hipStream_t stream) {
    const float* user_emb = (const float*)d_in[0];
    const float* item_emb = (const float*)d_in[1];
    const float* adj_vals = (const float*)d_in[2];
    const int*   adj_rows = (const int*)d_in[3];
    const int*   adj_cols = (const int*)d_in[4];
    const int*   users    = (const int*)d_in[5];
    const int*   items    = (const int*)d_in[6];
    float* out = (float*)d_out;

    const size_t node_u32 = (size_t)N_NODES * ROW_U32;   // fp8 rows: 32 u32 each
    char* p = (char*)d_ws;
    uint32* ego  = (uint32*)p;               p += node_u32 * sizeof(uint32);
    uint32* buf0 = (uint32*)p;               p += node_u32 * sizeof(uint32);
    uint32* buf1 = (uint32*)p;               p += node_u32 * sizeof(uint32);
    int* cursor       = (int*)p;             p += 640 * sizeof(int);          // 586 used
    int* bar          = (int*)p;             p += 1088 * sizeof(int);         // gen/root/leaves
    uint32* mark      = (uint32*)p;          p += ((N_NODES + 63) & ~63);     // 150016 B
    uint32* row_info4 = (uint32*)p;          p += (size_t)N_NODES * sizeof(uint32);
    uint64* binned    = (uint64*)p;          p += (size_t)NBUCKET * CAP * sizeof(uint64);
    uint32* csr4      = (uint32*)p;

    // ---- zero bucket cursors + barrier counters (one memset node) ----
    hipMemsetAsync(cursor, 0, (640 + 1088) * sizeof(int), stream);

    // ---- single persistent kernel: all 5 phases, 4 internal grid barriers ----
    mega<<<GRID, 256, 0, stream>>>(
        user_emb, item_emb, adj_vals, adj_rows, adj_cols, users, items,
        cursor, bar, binned, ego, buf0, buf1,
        (unsigned char*)mark, row_info4, csr4, out);
}